// Round 1
// baseline (322.020 us; speedup 1.0000x reference)
//
#include <hip/hip_runtime.h>
#include <hip/hip_bf16.h>

typedef __attribute__((ext_vector_type(8))) short short8;
typedef __attribute__((ext_vector_type(4))) float f32x4;

#define B_SZ 4
#define T_SZ 2048
#define C_SZ 1024
#define H_SZ 16
#define D_SZ 64

__device__ __forceinline__ unsigned short f2bf(float f){
  union { float f; unsigned u; } a; a.f = f;
  unsigned r = a.u + 0x7fffu + ((a.u >> 16) & 1u);
  return (unsigned short)(r >> 16);
}

__device__ __forceinline__ void gload16(const void* g, void* l){
  __builtin_amdgcn_global_load_lds(
      (const __attribute__((address_space(1))) void*)g,
      (__attribute__((address_space(3))) void*)l, 16, 0, 0);
}

// ---------- fp32 -> bf16 elementwise ----------
__global__ void cvt_bf16_kernel(const float* __restrict__ in,
                                unsigned short* __restrict__ out, int n4){
  int i = blockIdx.x * blockDim.x + threadIdx.x;
  if (i >= n4) return;
  const float4 v = ((const float4*)in)[i];
  ushort4 r;
  r.x = f2bf(v.x); r.y = f2bf(v.y); r.z = f2bf(v.z); r.w = f2bf(v.w);
  ((ushort4*)out)[i] = r;
}

// ---------- fp32 [K][N] -> bf16 [N][K] tiled transpose ----------
__global__ void tconv_kernel(const float* __restrict__ in,
                             unsigned short* __restrict__ out, int Kd, int Nd){
  __shared__ float t[32][33];
  const int n0 = blockIdx.x * 32, k0 = blockIdx.y * 32;
  const int tx = threadIdx.x, ty = threadIdx.y;
  #pragma unroll
  for (int i = 0; i < 32; i += 8)
    t[ty + i][tx] = in[(size_t)(k0 + ty + i) * Nd + n0 + tx];
  __syncthreads();
  #pragma unroll
  for (int i = 0; i < 32; i += 8)
    out[(size_t)(n0 + ty + i) * Kd + k0 + tx] = f2bf(t[tx][ty + i]);
}

// ---------- bf16 GEMM: C = A[M,K] * Bt[N,K]^T (+bias) ----------
// EPI 0: scatter to Q (scaled 0.125) / K [bh,t,d] and V [bh,d,t], bf16
// EPI 1: write fp32 C + bias to of[M,N]
template<int EPI>
__global__ __launch_bounds__(256, 2) void gemm_bt_kernel(
    const unsigned short* __restrict__ A, const unsigned short* __restrict__ Bt,
    const float* __restrict__ bias,
    unsigned short* __restrict__ o0, unsigned short* __restrict__ o1,
    unsigned short* __restrict__ o2, float* __restrict__ of,
    int M, int N, int K)
{
  __shared__ __align__(16) char lds[32768];
  const int tid = threadIdx.x, w = tid >> 6, lane = tid & 63;
  const int g = lane >> 4, c15 = lane & 15;
  const int wm = w >> 1, wn = w & 1;
  const int lr = lane >> 3, ls = lane & 7;
  const int soff = ((ls ^ lr) << 4);              // source-side swizzle
  const int bm = blockIdx.x, bn = blockIdx.y;
  f32x4 acc[4][4] = {};
  const char* Ab = (const char*)(A + (size_t)bm * 128 * K);
  const char* Bb = (const char*)(Bt + (size_t)bn * 128 * K);
  const int rowbytes = K * 2;

  for (int k0 = 0; k0 < K; k0 += 64){
    __syncthreads();
    #pragma unroll
    for (int c = 0; c < 4; c++){
      const int chunk = w * 4 + c;
      const int row = chunk * 8 + lr;
      gload16(Ab + (size_t)row * rowbytes + k0 * 2 + soff, lds + chunk * 1024);
      gload16(Bb + (size_t)row * rowbytes + k0 * 2 + soff, lds + 16384 + chunk * 1024);
    }
    __syncthreads();
    short8 af[4][2], bfr[4][2];
    #pragma unroll
    for (int i = 0; i < 4; i++){
      const int row = wm * 64 + i * 16 + c15;
      const int sw = (row & 7) << 4;
      af[i][0] = *(const short8*)(lds + row * 128 + ((g * 16) ^ sw));
      af[i][1] = *(const short8*)(lds + row * 128 + ((g * 16 + 64) ^ sw));
    }
    #pragma unroll
    for (int j = 0; j < 4; j++){
      const int row = wn * 64 + j * 16 + c15;
      const int sw = (row & 7) << 4;
      bfr[j][0] = *(const short8*)(lds + 16384 + row * 128 + ((g * 16) ^ sw));
      bfr[j][1] = *(const short8*)(lds + 16384 + row * 128 + ((g * 16 + 64) ^ sw));
    }
    #pragma unroll
    for (int i = 0; i < 4; i++)
      #pragma unroll
      for (int j = 0; j < 4; j++){
        acc[i][j] = __builtin_amdgcn_mfma_f32_16x16x32_bf16(af[i][0], bfr[j][0], acc[i][j], 0, 0, 0);
        acc[i][j] = __builtin_amdgcn_mfma_f32_16x16x32_bf16(af[i][1], bfr[j][1], acc[i][j], 0, 0, 0);
      }
  }

  const int mbase = bm * 128 + wm * 64;
  const int nbase = bn * 128 + wn * 64;
  if (EPI == 0){
    #pragma unroll
    for (int j = 0; j < 4; j++){
      const int n = nbase + j * 16 + c15;
      const float bv = bias[n];
      const int which = n >> 10, cc = n & 1023, h = cc >> 6, d = cc & 63;
      #pragma unroll
      for (int i = 0; i < 4; i++)
        #pragma unroll
        for (int r = 0; r < 4; r++){
          const int m = mbase + i * 16 + g * 4 + r;
          const int b = m >> 11, t = m & 2047;
          const float v = acc[i][j][r] + bv;
          if (which == 0)
            o0[((size_t)(b * H_SZ + h) * T_SZ + t) * D_SZ + d] = f2bf(v * 0.125f);
          else if (which == 1)
            o1[((size_t)(b * H_SZ + h) * T_SZ + t) * D_SZ + d] = f2bf(v);
          else
            o2[((size_t)(b * H_SZ + h) * D_SZ + d) * T_SZ + t] = f2bf(v);
        }
    }
  } else {
    #pragma unroll
    for (int j = 0; j < 4; j++){
      const int n = nbase + j * 16 + c15;
      const float bv = bias[n];
      #pragma unroll
      for (int i = 0; i < 4; i++)
        #pragma unroll
        for (int r = 0; r < 4; r++){
          const int m = mbase + i * 16 + g * 4 + r;
          of[(size_t)m * N + n] = acc[i][j][r] + bv;
        }
    }
  }
}

// ---------- causal flash attention ----------
// Q,K: [BH][T][D] bf16 (Q pre-scaled), Vt: [BH][D][T] bf16, Y: [B,T,C] bf16
__global__ __launch_bounds__(256, 2) void attn_kernel(
    const unsigned short* __restrict__ Q, const unsigned short* __restrict__ Kt,
    const unsigned short* __restrict__ Vt, unsigned short* __restrict__ Y)
{
  __shared__ __align__(16) char lds[24576];  // K:0..8K, V:8K..16K, P:16K..24K
  const int tid = threadIdx.x, w = tid >> 6, lane = tid & 63;
  const int g = lane >> 4, c15 = lane & 15;
  const int lr = lane >> 3, ls = lane & 7;
  const int soff = ((ls ^ lr) << 4);
  const int qt = blockIdx.x, bh = blockIdx.y;
  const unsigned short* Qb = Q + (size_t)bh * T_SZ * D_SZ;
  const unsigned short* Kb = Kt + (size_t)bh * T_SZ * D_SZ;
  const unsigned short* Vb = Vt + (size_t)bh * D_SZ * T_SZ;

  const int qrow = qt * 64 + w * 16 + c15;
  const short8 qf0 = *(const short8*)(Qb + (size_t)qrow * D_SZ + g * 8);
  const short8 qf1 = *(const short8*)(Qb + (size_t)qrow * D_SZ + g * 8 + 32);

  f32x4 oacc[4] = {};
  float mst[4] = {-1e30f, -1e30f, -1e30f, -1e30f};
  float lst[4] = {0.f, 0.f, 0.f, 0.f};

  for (int kt = 0; kt <= qt; kt++){
    __syncthreads();
    #pragma unroll
    for (int c = 0; c < 2; c++){
      const int chunk = w * 2 + c;
      const int r = chunk * 8 + lr;
      gload16((const char*)Kb + ((size_t)(kt * 64 + r) * D_SZ) * 2 + soff, lds + chunk * 1024);
      gload16((const char*)Vb + ((size_t)r * T_SZ + kt * 64) * 2 + soff, lds + 8192 + chunk * 1024);
    }
    __syncthreads();

    f32x4 s[4];
    #pragma unroll
    for (int j = 0; j < 4; j++){
      const int row = j * 16 + c15;
      const int sw = (row & 7) << 4;
      const short8 k0 = *(const short8*)(lds + row * 128 + ((g * 16) ^ sw));
      const short8 k1 = *(const short8*)(lds + row * 128 + ((g * 16 + 64) ^ sw));
      f32x4 z = {0.f, 0.f, 0.f, 0.f};
      z = __builtin_amdgcn_mfma_f32_16x16x32_bf16(qf0, k0, z, 0, 0, 0);
      s[j] = __builtin_amdgcn_mfma_f32_16x16x32_bf16(qf1, k1, z, 0, 0, 0);
    }

    if (kt == qt){
      const int qloc = w * 16 + g * 4;
      #pragma unroll
      for (int j = 0; j < 4; j++){
        const int col = j * 16 + c15;
        #pragma unroll
        for (int r = 0; r < 4; r++)
          if (col > qloc + r) s[j][r] = -1e30f;
      }
    }

    float fac[4];
    #pragma unroll
    for (int r = 0; r < 4; r++){
      float rm = fmaxf(fmaxf(s[0][r], s[1][r]), fmaxf(s[2][r], s[3][r]));
      rm = fmaxf(rm, __shfl_xor(rm, 1));
      rm = fmaxf(rm, __shfl_xor(rm, 2));
      rm = fmaxf(rm, __shfl_xor(rm, 4));
      rm = fmaxf(rm, __shfl_xor(rm, 8));
      const float nm = fmaxf(mst[r], rm);
      fac[r] = __expf(mst[r] - nm);
      mst[r] = nm;
    }

    float rsum[4] = {0.f, 0.f, 0.f, 0.f};
    #pragma unroll
    for (int j = 0; j < 4; j++)
      #pragma unroll
      for (int r = 0; r < 4; r++){
        const float p = __expf(s[j][r] - mst[r]);
        s[j][r] = p;
        rsum[r] += p;
      }

    // write P strip (wave-private) to swizzled LDS
    #pragma unroll
    for (int j = 0; j < 4; j++)
      #pragma unroll
      for (int r = 0; r < 4; r++){
        const int row = w * 16 + g * 4 + r;
        const int cb = (j * 16 + c15) * 2;
        *(unsigned short*)(lds + 16384 + row * 128 + (cb ^ ((row & 7) << 4))) = f2bf(s[j][r]);
      }

    #pragma unroll
    for (int r = 0; r < 4; r++){
      rsum[r] += __shfl_xor(rsum[r], 1);
      rsum[r] += __shfl_xor(rsum[r], 2);
      rsum[r] += __shfl_xor(rsum[r], 4);
      rsum[r] += __shfl_xor(rsum[r], 8);
      lst[r] = lst[r] * fac[r] + rsum[r];
    }
    #pragma unroll
    for (int j = 0; j < 4; j++)
      #pragma unroll
      for (int r = 0; r < 4; r++)
        oacc[j][r] *= fac[r];

    const int prow = w * 16 + c15;
    const int psw = (prow & 7) << 4;
    const short8 pf0 = *(const short8*)(lds + 16384 + prow * 128 + ((g * 16) ^ psw));
    const short8 pf1 = *(const short8*)(lds + 16384 + prow * 128 + ((g * 16 + 64) ^ psw));

    #pragma unroll
    for (int j = 0; j < 4; j++){
      const int row = j * 16 + c15;
      const int sw = (row & 7) << 4;
      const short8 v0 = *(const short8*)(lds + 8192 + row * 128 + ((g * 16) ^ sw));
      const short8 v1 = *(const short8*)(lds + 8192 + row * 128 + ((g * 16 + 64) ^ sw));
      oacc[j] = __builtin_amdgcn_mfma_f32_16x16x32_bf16(pf0, v0, oacc[j], 0, 0, 0);
      oacc[j] = __builtin_amdgcn_mfma_f32_16x16x32_bf16(pf1, v1, oacc[j], 0, 0, 0);
    }
  }

  const int b = bh >> 4, h = bh & 15;
  float inv[4];
  #pragma unroll
  for (int r = 0; r < 4; r++) inv[r] = 1.f / lst[r];
  #pragma unroll
  for (int j = 0; j < 4; j++)
    #pragma unroll
    for (int r = 0; r < 4; r++){
      const int row = qt * 64 + w * 16 + g * 4 + r;
      const int col = h * 64 + j * 16 + c15;
      Y[((size_t)(b * T_SZ + row)) * C_SZ + col] = f2bf(oacc[j][r] * inv[r]);
    }
}

extern "C" void kernel_launch(void* const* d_in, const int* in_sizes, int n_in,
                              void* d_out, int out_size, void* d_ws, size_t ws_size,
                              hipStream_t stream)
{
  const float* x      = (const float*)d_in[0];
  const float* w_qkv  = (const float*)d_in[1];
  const float* b_qkv  = (const float*)d_in[2];
  const float* w_proj = (const float*)d_in[3];
  const float* b_proj = (const float*)d_in[4];
  float* out = (float*)d_out;
  char* ws = (char*)d_ws;

  unsigned short* xb     = (unsigned short*)(ws);               // 16 MB
  unsigned short* wqkvT  = (unsigned short*)(ws + 16777216);    // 6 MB
  unsigned short* wprojT = (unsigned short*)(ws + 23068672);    // 2 MB
  unsigned short* Qw     = (unsigned short*)(ws + 25165824);    // 16 MB
  unsigned short* Kw     = (unsigned short*)(ws + 41943040);    // 16 MB
  unsigned short* Vw     = (unsigned short*)(ws + 58720256);    // 16 MB (transposed [bh,d,t])
  unsigned short* Yw     = (unsigned short*)(ws + 75497472);    // 16 MB

  cvt_bf16_kernel<<<8192, 256, 0, stream>>>(x, xb, 8388608 / 4);
  tconv_kernel<<<dim3(96, 32), dim3(32, 8), 0, stream>>>(w_qkv, wqkvT, 1024, 3072);
  tconv_kernel<<<dim3(32, 32), dim3(32, 8), 0, stream>>>(w_proj, wprojT, 1024, 1024);
  gemm_bt_kernel<0><<<dim3(64, 24), 256, 0, stream>>>(xb, wqkvT, b_qkv, Qw, Kw, Vw, nullptr, 8192, 3072, 1024);
  attn_kernel<<<dim3(32, 64), 256, 0, stream>>>(Qw, Kw, Vw, Yw);
  gemm_bt_kernel<1><<<dim3(64, 8), 256, 0, stream>>>(Yw, wprojT, b_proj, nullptr, nullptr, nullptr, out, 8192, 1024, 1024);
}

// Round 3
// 235.400 us; speedup vs baseline: 1.3680x; 1.3680x over previous
//
#include <hip/hip_runtime.h>
#include <hip/hip_bf16.h>

typedef __attribute__((ext_vector_type(8))) short short8;
typedef __attribute__((ext_vector_type(4))) float f32x4;

#define B_SZ 4
#define T_SZ 2048
#define C_SZ 1024
#define H_SZ 16
#define D_SZ 64

__device__ __forceinline__ unsigned short f2bf(float f){
  union { float f; unsigned u; } a; a.f = f;
  unsigned r = a.u + 0x7fffu + ((a.u >> 16) & 1u);
  return (unsigned short)(r >> 16);
}

__device__ __forceinline__ float fexp2(float x){
  return __builtin_amdgcn_exp2f(x);
}

__device__ __forceinline__ void gload16(const void* g, void* l){
  __builtin_amdgcn_global_load_lds(
      (const __attribute__((address_space(1))) void*)g,
      (__attribute__((address_space(3))) void*)l, 16, 0, 0);
}

// ---------- fp32 -> bf16 elementwise ----------
__global__ void cvt_bf16_kernel(const float* __restrict__ in,
                                unsigned short* __restrict__ out, int n4){
  int i = blockIdx.x * blockDim.x + threadIdx.x;
  if (i >= n4) return;
  const float4 v = ((const float4*)in)[i];
  ushort4 r;
  r.x = f2bf(v.x); r.y = f2bf(v.y); r.z = f2bf(v.z); r.w = f2bf(v.w);
  ((ushort4*)out)[i] = r;
}

// ---------- fp32 [K][N] -> bf16 [N][K] tiled transpose ----------
__global__ void tconv_kernel(const float* __restrict__ in,
                             unsigned short* __restrict__ out, int Kd, int Nd){
  __shared__ float t[32][33];
  const int n0 = blockIdx.x * 32, k0 = blockIdx.y * 32;
  const int tx = threadIdx.x, ty = threadIdx.y;
  #pragma unroll
  for (int i = 0; i < 32; i += 8)
    t[ty + i][tx] = in[(size_t)(k0 + ty + i) * Nd + n0 + tx];
  __syncthreads();
  #pragma unroll
  for (int i = 0; i < 32; i += 8)
    out[(size_t)(n0 + ty + i) * Kd + k0 + tx] = f2bf(t[tx][ty + i]);
}

// ---------- bf16 GEMM: C = A[M,K] * Bt[N,K]^T (+bias) ----------
template<int EPI>
__global__ __launch_bounds__(256, 2) void gemm_bt_kernel(
    const unsigned short* __restrict__ A, const unsigned short* __restrict__ Bt,
    const float* __restrict__ bias,
    unsigned short* __restrict__ o0, unsigned short* __restrict__ o1,
    unsigned short* __restrict__ o2, float* __restrict__ of,
    int M, int N, int K)
{
  __shared__ __align__(16) char lds[32768];
  const int tid = threadIdx.x, w = tid >> 6, lane = tid & 63;
  const int g = lane >> 4, c15 = lane & 15;
  const int wm = w >> 1, wn = w & 1;
  const int lr = lane >> 3, ls = lane & 7;
  const int soff = ((ls ^ lr) << 4);              // source-side swizzle
  const int bm = blockIdx.x, bn = blockIdx.y;
  f32x4 acc[4][4] = {};
  const char* Ab = (const char*)(A + (size_t)bm * 128 * K);
  const char* Bb = (const char*)(Bt + (size_t)bn * 128 * K);
  const int rowbytes = K * 2;

  for (int k0 = 0; k0 < K; k0 += 64){
    __syncthreads();
    #pragma unroll
    for (int c = 0; c < 4; c++){
      const int chunk = w * 4 + c;
      const int row = chunk * 8 + lr;
      gload16(Ab + (size_t)row * rowbytes + k0 * 2 + soff, lds + chunk * 1024);
      gload16(Bb + (size_t)row * rowbytes + k0 * 2 + soff, lds + 16384 + chunk * 1024);
    }
    __syncthreads();
    short8 af[4][2], bfr[4][2];
    #pragma unroll
    for (int i = 0; i < 4; i++){
      const int row = wm * 64 + i * 16 + c15;
      const int sw = (row & 7) << 4;
      af[i][0] = *(const short8*)(lds + row * 128 + ((g * 16) ^ sw));
      af[i][1] = *(const short8*)(lds + row * 128 + ((g * 16 + 64) ^ sw));
    }
    #pragma unroll
    for (int j = 0; j < 4; j++){
      const int row = wn * 64 + j * 16 + c15;
      const int sw = (row & 7) << 4;
      bfr[j][0] = *(const short8*)(lds + 16384 + row * 128 + ((g * 16) ^ sw));
      bfr[j][1] = *(const short8*)(lds + 16384 + row * 128 + ((g * 16 + 64) ^ sw));
    }
    #pragma unroll
    for (int i = 0; i < 4; i++)
      #pragma unroll
      for (int j = 0; j < 4; j++){
        acc[i][j] = __builtin_amdgcn_mfma_f32_16x16x32_bf16(af[i][0], bfr[j][0], acc[i][j], 0, 0, 0);
        acc[i][j] = __builtin_amdgcn_mfma_f32_16x16x32_bf16(af[i][1], bfr[j][1], acc[i][j], 0, 0, 0);
      }
  }

  const int mbase = bm * 128 + wm * 64;
  const int nbase = bn * 128 + wn * 64;
  if (EPI == 0){
    // Q scale folds 1/sqrt(64) * log2(e) so attention can use exp2
    const float QSCALE = 0.125f * 1.4426950408889634f;
    #pragma unroll
    for (int j = 0; j < 4; j++){
      const int n = nbase + j * 16 + c15;
      const float bv = bias[n];
      const int which = n >> 10, cc = n & 1023, h = cc >> 6, d = cc & 63;
      #pragma unroll
      for (int i = 0; i < 4; i++)
        #pragma unroll
        for (int r = 0; r < 4; r++){
          const int m = mbase + i * 16 + g * 4 + r;
          const int b = m >> 11, t = m & 2047;
          const float v = acc[i][j][r] + bv;
          if (which == 0)
            o0[((size_t)(b * H_SZ + h) * T_SZ + t) * D_SZ + d] = f2bf(v * QSCALE);
          else if (which == 1)
            o1[((size_t)(b * H_SZ + h) * T_SZ + t) * D_SZ + d] = f2bf(v);
          else
            o2[((size_t)(b * H_SZ + h) * D_SZ + d) * T_SZ + t] = f2bf(v);
        }
    }
  } else {
    #pragma unroll
    for (int j = 0; j < 4; j++){
      const int n = nbase + j * 16 + c15;
      const float bv = bias[n];
      #pragma unroll
      for (int i = 0; i < 4; i++)
        #pragma unroll
        for (int r = 0; r < 4; r++){
          const int m = mbase + i * 16 + g * 4 + r;
          of[(size_t)m * N + n] = acc[i][j][r] + bv;
        }
    }
  }
}

// ---------- causal flash attention, balanced pairs + double-buffered K/V ----------
// Q,K: [BH][T][D] bf16 (Q pre-scaled by 1/8*log2e), Vt: [BH][D][T] bf16, Y: [B,T,C] bf16
// LDS: K0 0..8K | K1 8..16K | V0 16..24K | V1 24..32K | P 32..40K
__global__ __launch_bounds__(256, 4) void attn_kernel(
    const unsigned short* __restrict__ Q, const unsigned short* __restrict__ Kt,
    const unsigned short* __restrict__ Vt, unsigned short* __restrict__ Y)
{
  __shared__ __align__(16) char lds[40960];
  const int tid = threadIdx.x, w = tid >> 6, lane = tid & 63;
  const int g = lane >> 4, c15 = lane & 15;
  const int lr = lane >> 3, ls = lane & 7;
  const int soff = ((ls ^ lr) << 4);
  const int pair = blockIdx.x, bh = blockIdx.y;
  const unsigned short* Qb = Q + (size_t)bh * T_SZ * D_SZ;
  const unsigned short* Kb = Kt + (size_t)bh * T_SZ * D_SZ;
  const unsigned short* Vb = Vt + (size_t)bh * D_SZ * T_SZ;
  const int b = bh >> 4, h = bh & 15;

  #pragma unroll
  for (int pass = 0; pass < 2; pass++){
    const int qt = pass == 0 ? pair : (31 - pair);

    const int qrow = qt * 64 + w * 16 + c15;
    const short8 qf0 = *(const short8*)(Qb + (size_t)qrow * D_SZ + g * 8);
    const short8 qf1 = *(const short8*)(Qb + (size_t)qrow * D_SZ + g * 8 + 32);

    f32x4 oacc[4] = {};
    float mst[4] = {-1e30f, -1e30f, -1e30f, -1e30f};
    float lst[4] = {0.f, 0.f, 0.f, 0.f};

    // prologue: stage tile 0 into buffer 0
    __syncthreads();   // protect LDS from previous pass readers
    #pragma unroll
    for (int c = 0; c < 2; c++){
      const int chunk = w * 2 + c;
      const int r = chunk * 8 + lr;
      gload16((const char*)Kb + ((size_t)r * D_SZ) * 2 + soff, lds + chunk * 1024);
      gload16((const char*)Vb + ((size_t)r * T_SZ) * 2 + soff, lds + 16384 + chunk * 1024);
    }
    __syncthreads();   // tile 0 resident

    int cur = 0;
    for (int kt = 0; kt <= qt; kt++){
      // prefetch next tile into buf^1 (stays in flight across compute)
      if (kt < qt){
        const int nb = (cur ^ 1) * 8192;
        #pragma unroll
        for (int c = 0; c < 2; c++){
          const int chunk = w * 2 + c;
          const int r = chunk * 8 + lr;
          gload16((const char*)Kb + ((size_t)((kt + 1) * 64 + r) * D_SZ) * 2 + soff,
                  lds + nb + chunk * 1024);
          gload16((const char*)Vb + ((size_t)r * T_SZ + (kt + 1) * 64) * 2 + soff,
                  lds + 16384 + nb + chunk * 1024);
        }
      }

      const char* kbase = lds + cur * 8192;
      const char* vbase = lds + 16384 + cur * 8192;

      f32x4 s[4];
      #pragma unroll
      for (int j = 0; j < 4; j++){
        const int row = j * 16 + c15;
        const int sw = (row & 7) << 4;
        const short8 k0 = *(const short8*)(kbase + row * 128 + ((g * 16) ^ sw));
        const short8 k1 = *(const short8*)(kbase + row * 128 + ((g * 16 + 64) ^ sw));
        f32x4 z = {0.f, 0.f, 0.f, 0.f};
        z = __builtin_amdgcn_mfma_f32_16x16x32_bf16(qf0, k0, z, 0, 0, 0);
        s[j] = __builtin_amdgcn_mfma_f32_16x16x32_bf16(qf1, k1, z, 0, 0, 0);
      }

      if (kt == qt){
        const int qloc = w * 16 + g * 4;
        #pragma unroll
        for (int j = 0; j < 4; j++){
          const int col = j * 16 + c15;
          #pragma unroll
          for (int r = 0; r < 4; r++)
            if (col > qloc + r) s[j][r] = -1e30f;
        }
      }

      float fac[4];
      #pragma unroll
      for (int r = 0; r < 4; r++){
        float rm = fmaxf(fmaxf(s[0][r], s[1][r]), fmaxf(s[2][r], s[3][r]));
        rm = fmaxf(rm, __shfl_xor(rm, 1));
        rm = fmaxf(rm, __shfl_xor(rm, 2));
        rm = fmaxf(rm, __shfl_xor(rm, 4));
        rm = fmaxf(rm, __shfl_xor(rm, 8));
        const float nm = fmaxf(mst[r], rm);
        fac[r] = fexp2(mst[r] - nm);
        mst[r] = nm;
      }

      float rsum[4] = {0.f, 0.f, 0.f, 0.f};
      #pragma unroll
      for (int j = 0; j < 4; j++)
        #pragma unroll
        for (int r = 0; r < 4; r++){
          const float p = fexp2(s[j][r] - mst[r]);
          s[j][r] = p;
          rsum[r] += p;
        }

      // write P strip (wave-private rows) to swizzled LDS
      #pragma unroll
      for (int j = 0; j < 4; j++)
        #pragma unroll
        for (int r = 0; r < 4; r++){
          const int row = w * 16 + g * 4 + r;
          const int cb = (j * 16 + c15) * 2;
          *(unsigned short*)(lds + 32768 + row * 128 + (cb ^ ((row & 7) << 4))) = f2bf(s[j][r]);
        }

      #pragma unroll
      for (int r = 0; r < 4; r++){
        rsum[r] += __shfl_xor(rsum[r], 1);
        rsum[r] += __shfl_xor(rsum[r], 2);
        rsum[r] += __shfl_xor(rsum[r], 4);
        rsum[r] += __shfl_xor(rsum[r], 8);
        lst[r] = lst[r] * fac[r] + rsum[r];
      }
      #pragma unroll
      for (int j = 0; j < 4; j++)
        #pragma unroll
        for (int r = 0; r < 4; r++)
          oacc[j][r] *= fac[r];

      const int prow = w * 16 + c15;
      const int psw = (prow & 7) << 4;
      const short8 pf0 = *(const short8*)(lds + 32768 + prow * 128 + ((g * 16) ^ psw));
      const short8 pf1 = *(const short8*)(lds + 32768 + prow * 128 + ((g * 16 + 64) ^ psw));

      #pragma unroll
      for (int j = 0; j < 4; j++){
        const int row = j * 16 + c15;
        const int sw = (row & 7) << 4;
        const short8 v0 = *(const short8*)(vbase + row * 128 + ((g * 16) ^ sw));
        const short8 v1 = *(const short8*)(vbase + row * 128 + ((g * 16 + 64) ^ sw));
        oacc[j] = __builtin_amdgcn_mfma_f32_16x16x32_bf16(pf0, v0, oacc[j], 0, 0, 0);
        oacc[j] = __builtin_amdgcn_mfma_f32_16x16x32_bf16(pf1, v1, oacc[j], 0, 0, 0);
      }

      __syncthreads();   // drains prefetch vmcnt + compute lgkm; next tile ready
      cur ^= 1;
    }

    float inv[4];
    #pragma unroll
    for (int r = 0; r < 4; r++) inv[r] = 1.f / lst[r];
    #pragma unroll
    for (int j = 0; j < 4; j++)
      #pragma unroll
      for (int r = 0; r < 4; r++){
        const int row = qt * 64 + w * 16 + g * 4 + r;
        const int col = h * 64 + j * 16 + c15;
        Y[((size_t)(b * T_SZ + row)) * C_SZ + col] = f2bf(oacc[j][r] * inv[r]);
      }
  }
}

extern "C" void kernel_launch(void* const* d_in, const int* in_sizes, int n_in,
                              void* d_out, int out_size, void* d_ws, size_t ws_size,
                              hipStream_t stream)
{
  const float* x      = (const float*)d_in[0];
  const float* w_qkv  = (const float*)d_in[1];
  const float* b_qkv  = (const float*)d_in[2];
  const float* w_proj = (const float*)d_in[3];
  const float* b_proj = (const float*)d_in[4];
  float* out = (float*)d_out;
  char* ws = (char*)d_ws;

  unsigned short* xb     = (unsigned short*)(ws);               // 16 MB
  unsigned short* wqkvT  = (unsigned short*)(ws + 16777216);    // 6 MB
  unsigned short* wprojT = (unsigned short*)(ws + 23068672);    // 2 MB
  unsigned short* Qw     = (unsigned short*)(ws + 25165824);    // 16 MB
  unsigned short* Kw     = (unsigned short*)(ws + 41943040);    // 16 MB
  unsigned short* Vw     = (unsigned short*)(ws + 58720256);    // 16 MB (transposed [bh,d,t])
  unsigned short* Yw     = (unsigned short*)(ws + 75497472);    // 16 MB

  cvt_bf16_kernel<<<8192, 256, 0, stream>>>(x, xb, 8388608 / 4);
  tconv_kernel<<<dim3(96, 32), dim3(32, 8), 0, stream>>>(w_qkv, wqkvT, 1024, 3072);
  tconv_kernel<<<dim3(32, 32), dim3(32, 8), 0, stream>>>(w_proj, wprojT, 1024, 1024);
  gemm_bt_kernel<0><<<dim3(64, 24), 256, 0, stream>>>(xb, wqkvT, b_qkv, Qw, Kw, Vw, nullptr, 8192, 3072, 1024);
  attn_kernel<<<dim3(16, 64), 256, 0, stream>>>(Qw, Kw, Vw, Yw);
  gemm_bt_kernel<1><<<dim3(64, 8), 256, 0, stream>>>(Yw, wprojT, b_proj, nullptr, nullptr, nullptr, out, 8192, 1024, 1024);
}

// Round 4
// 194.257 us; speedup vs baseline: 1.6577x; 1.2118x over previous
//
#include <hip/hip_runtime.h>
#include <hip/hip_bf16.h>

typedef __attribute__((ext_vector_type(8))) short short8;
typedef __attribute__((ext_vector_type(4))) float f32x4;
typedef __attribute__((ext_vector_type(4))) int i32x4;

#define B_SZ 4
#define T_SZ 2048
#define C_SZ 1024
#define H_SZ 16
#define D_SZ 64

__device__ __forceinline__ unsigned short f2bf(float f){
  union { float f; unsigned u; } a; a.f = f;
  unsigned r = a.u + 0x7fffu + ((a.u >> 16) & 1u);
  return (unsigned short)(r >> 16);
}

__device__ __forceinline__ float fexp2(float x){
  return __builtin_amdgcn_exp2f(x);
}

__device__ __forceinline__ unsigned cvtpk(float lo, float hi){
  unsigned r;
  asm("v_cvt_pk_bf16_f32 %0, %1, %2" : "=v"(r) : "v"(lo), "v"(hi));
  return r;
}

__device__ __forceinline__ void gload16(const void* g, void* l){
  __builtin_amdgcn_global_load_lds(
      (const __attribute__((address_space(1))) void*)g,
      (__attribute__((address_space(3))) void*)l, 16, 0, 0);
}

// ---------- fp32 -> bf16 elementwise ----------
__global__ void cvt_bf16_kernel(const float* __restrict__ in,
                                unsigned short* __restrict__ out, int n4){
  int i = blockIdx.x * blockDim.x + threadIdx.x;
  if (i >= n4) return;
  const float4 v = ((const float4*)in)[i];
  ushort4 r;
  r.x = f2bf(v.x); r.y = f2bf(v.y); r.z = f2bf(v.z); r.w = f2bf(v.w);
  ((ushort4*)out)[i] = r;
}

// ---------- fp32 [K][N] -> bf16 [N][K] tiled transpose ----------
__global__ void tconv_kernel(const float* __restrict__ in,
                             unsigned short* __restrict__ out, int Kd, int Nd){
  __shared__ float t[32][33];
  const int n0 = blockIdx.x * 32, k0 = blockIdx.y * 32;
  const int tx = threadIdx.x, ty = threadIdx.y;
  #pragma unroll
  for (int i = 0; i < 32; i += 8)
    t[ty + i][tx] = in[(size_t)(k0 + ty + i) * Nd + n0 + tx];
  __syncthreads();
  #pragma unroll
  for (int i = 0; i < 32; i += 8)
    out[(size_t)(n0 + ty + i) * Kd + k0 + tx] = f2bf(t[tx][ty + i]);
}

// ---------- bf16 GEMM: C = A[M,K] * Bt[N,K]^T (+bias) ----------
template<int EPI>
__global__ __launch_bounds__(256, 2) void gemm_bt_kernel(
    const unsigned short* __restrict__ A, const unsigned short* __restrict__ Bt,
    const float* __restrict__ bias,
    unsigned short* __restrict__ o0, unsigned short* __restrict__ o1,
    unsigned short* __restrict__ o2, float* __restrict__ of,
    int M, int N, int K)
{
  __shared__ __align__(16) char lds[32768];
  const int tid = threadIdx.x, w = tid >> 6, lane = tid & 63;
  const int g = lane >> 4, c15 = lane & 15;
  const int wm = w >> 1, wn = w & 1;
  const int lr = lane >> 3, ls = lane & 7;
  const int soff = ((ls ^ lr) << 4);              // source-side swizzle
  const int bm = blockIdx.x, bn = blockIdx.y;
  f32x4 acc[4][4] = {};
  const char* Ab = (const char*)(A + (size_t)bm * 128 * K);
  const char* Bb = (const char*)(Bt + (size_t)bn * 128 * K);
  const int rowbytes = K * 2;

  for (int k0 = 0; k0 < K; k0 += 64){
    __syncthreads();
    #pragma unroll
    for (int c = 0; c < 4; c++){
      const int chunk = w * 4 + c;
      const int row = chunk * 8 + lr;
      gload16(Ab + (size_t)row * rowbytes + k0 * 2 + soff, lds + chunk * 1024);
      gload16(Bb + (size_t)row * rowbytes + k0 * 2 + soff, lds + 16384 + chunk * 1024);
    }
    __syncthreads();
    short8 af[4][2], bfr[4][2];
    #pragma unroll
    for (int i = 0; i < 4; i++){
      const int row = wm * 64 + i * 16 + c15;
      const int sw = (row & 7) << 4;
      af[i][0] = *(const short8*)(lds + row * 128 + ((g * 16) ^ sw));
      af[i][1] = *(const short8*)(lds + row * 128 + ((g * 16 + 64) ^ sw));
    }
    #pragma unroll
    for (int j = 0; j < 4; j++){
      const int row = wn * 64 + j * 16 + c15;
      const int sw = (row & 7) << 4;
      bfr[j][0] = *(const short8*)(lds + 16384 + row * 128 + ((g * 16) ^ sw));
      bfr[j][1] = *(const short8*)(lds + 16384 + row * 128 + ((g * 16 + 64) ^ sw));
    }
    #pragma unroll
    for (int i = 0; i < 4; i++)
      #pragma unroll
      for (int j = 0; j < 4; j++){
        acc[i][j] = __builtin_amdgcn_mfma_f32_16x16x32_bf16(af[i][0], bfr[j][0], acc[i][j], 0, 0, 0);
        acc[i][j] = __builtin_amdgcn_mfma_f32_16x16x32_bf16(af[i][1], bfr[j][1], acc[i][j], 0, 0, 0);
      }
  }

  const int mbase = bm * 128 + wm * 64;
  const int nbase = bn * 128 + wn * 64;
  if (EPI == 0){
    // Q scale folds 1/sqrt(64) * log2(e) so attention can use exp2
    const float QSCALE = 0.125f * 1.4426950408889634f;
    #pragma unroll
    for (int j = 0; j < 4; j++){
      const int n = nbase + j * 16 + c15;
      const float bv = bias[n];
      const int which = n >> 10, cc = n & 1023, h = cc >> 6, d = cc & 63;
      #pragma unroll
      for (int i = 0; i < 4; i++)
        #pragma unroll
        for (int r = 0; r < 4; r++){
          const int m = mbase + i * 16 + g * 4 + r;
          const int b = m >> 11, t = m & 2047;
          const float v = acc[i][j][r] + bv;
          if (which == 0)
            o0[((size_t)(b * H_SZ + h) * T_SZ + t) * D_SZ + d] = f2bf(v * QSCALE);
          else if (which == 1)
            o1[((size_t)(b * H_SZ + h) * T_SZ + t) * D_SZ + d] = f2bf(v);
          else
            o2[((size_t)(b * H_SZ + h) * D_SZ + d) * T_SZ + t] = f2bf(v);
        }
    }
  } else {
    #pragma unroll
    for (int j = 0; j < 4; j++){
      const int n = nbase + j * 16 + c15;
      const float bv = bias[n];
      #pragma unroll
      for (int i = 0; i < 4; i++)
        #pragma unroll
        for (int r = 0; r < 4; r++){
          const int m = mbase + i * 16 + g * 4 + r;
          of[(size_t)m * N + n] = acc[i][j][r] + bv;
        }
    }
  }
}

// ---------- causal flash attention, swapped QK^T, P fully in registers ----------
// Q,K: [BH][T][D] bf16 (Q pre-scaled by 1/8*log2e), Vt: [BH][D][T] bf16, Y: [B,T,C] bf16
// LDS: K0 0..8K | K1 8..16K | V0 16..24K | V1 24..32K
// K-tile rows stored pi-permuted: lds row i holds K row pi(i),
// pi(i) = ((i>>2)&3)*8 + ((i>>4)&1)*4 + (i>>5)*32 + (i&3)
// => after swapped QK^T, lane (g,c15) holds P[q=w*16+c15][k = g*8+(j&1)*4+(j>>1)*32+r]
//    which packs directly into PV's A-fragment (natural k order). No P LDS.
__global__ __launch_bounds__(256, 4) void attn_kernel(
    const unsigned short* __restrict__ Q, const unsigned short* __restrict__ Kt,
    const unsigned short* __restrict__ Vt, unsigned short* __restrict__ Y)
{
  __shared__ __align__(16) char lds[32768];
  const int tid = threadIdx.x, w = tid >> 6, lane = tid & 63;
  const int g = lane >> 4, c15 = lane & 15;
  const int lr = lane >> 3, ls = lane & 7;
  const int soff = ((ls ^ lr) << 4);
  const int pair = blockIdx.x, bh = blockIdx.y;
  const unsigned short* Qb = Q + (size_t)bh * T_SZ * D_SZ;
  const unsigned short* Kb = Kt + (size_t)bh * T_SZ * D_SZ;
  const unsigned short* Vb = Vt + (size_t)bh * D_SZ * T_SZ;
  const int b = bh >> 4, h = bh & 15;

  auto stage = [&](int ktile, int buf){
    #pragma unroll
    for (int c = 0; c < 2; c++){
      const int chunk = w * 2 + c;
      const int i = chunk * 8 + lr;
      const int pi = ((i >> 2) & 3) * 8 + ((i >> 4) & 1) * 4 + (i >> 5) * 32 + (i & 3);
      gload16((const char*)Kb + ((size_t)(ktile * 64 + pi) * D_SZ) * 2 + soff,
              lds + buf * 8192 + chunk * 1024);
      gload16((const char*)Vb + ((size_t)i * T_SZ + ktile * 64) * 2 + soff,
              lds + 16384 + buf * 8192 + chunk * 1024);
    }
  };

  #pragma unroll
  for (int pass = 0; pass < 2; pass++){
    const int qt = pass == 0 ? pair : (31 - pair);

    const int qrow = qt * 64 + w * 16 + c15;
    const short8 qf0 = *(const short8*)(Qb + (size_t)qrow * D_SZ + g * 8);
    const short8 qf1 = *(const short8*)(Qb + (size_t)qrow * D_SZ + g * 8 + 32);

    f32x4 oacc[4] = {};
    float mst = -1e30f, lst = 0.f;

    __syncthreads();   // protect LDS from previous pass readers
    stage(0, 0);
    __syncthreads();   // tile 0 resident

    int cur = 0;
    for (int kt = 0; kt <= qt; kt++){
      if (kt < qt) stage(kt + 1, cur ^ 1);   // prefetch stays in flight across compute

      const char* kbase = lds + cur * 8192;
      const char* vbase = lds + 16384 + cur * 8192;

      // QK^T swapped: A = K-frag, B = Q-frag -> s[j][r] = P-row of q=w*16+c15
      f32x4 s[4];
      __builtin_amdgcn_s_setprio(1);
      #pragma unroll
      for (int j = 0; j < 4; j++){
        const int row = j * 16 + c15;
        const int sw = (row & 7) << 4;
        const short8 k0 = *(const short8*)(kbase + row * 128 + ((g * 16) ^ sw));
        const short8 k1 = *(const short8*)(kbase + row * 128 + ((g * 16 + 64) ^ sw));
        f32x4 z = {0.f, 0.f, 0.f, 0.f};
        z = __builtin_amdgcn_mfma_f32_16x16x32_bf16(k0, qf0, z, 0, 0, 0);
        s[j] = __builtin_amdgcn_mfma_f32_16x16x32_bf16(k1, qf1, z, 0, 0, 0);
      }
      __builtin_amdgcn_s_setprio(0);

      if (kt == qt){
        const int qloc = w * 16 + c15;
        #pragma unroll
        for (int j = 0; j < 4; j++){
          const int kb = g * 8 + (j & 1) * 4 + (j >> 1) * 32;
          #pragma unroll
          for (int r = 0; r < 4; r++)
            if (kb + r > qloc) s[j][r] = -1e30f;
        }
      }

      // scalar online softmax for this lane's q-row
      float rm = s[0][0];
      #pragma unroll
      for (int j = 0; j < 4; j++)
        #pragma unroll
        for (int r = 0; r < 4; r++) rm = fmaxf(rm, s[j][r]);
      rm = fmaxf(rm, __shfl_xor(rm, 16));
      rm = fmaxf(rm, __shfl_xor(rm, 32));
      const float nm = fmaxf(mst, rm);
      const float fac = fexp2(mst - nm);
      mst = nm;

      float rs = 0.f;
      #pragma unroll
      for (int j = 0; j < 4; j++)
        #pragma unroll
        for (int r = 0; r < 4; r++){
          const float p = fexp2(s[j][r] - mst);
          s[j][r] = p;
          rs += p;
        }
      rs += __shfl_xor(rs, 16);
      rs += __shfl_xor(rs, 32);
      lst = lst * fac + rs;

      // redistribute fac to oacc's row layout (row q = w*16 + g*4 + r)
      #pragma unroll
      for (int r = 0; r < 4; r++){
        const float facr = __shfl(fac, (lane & 48) | (g * 4 + r));
        #pragma unroll
        for (int j = 0; j < 4; j++) oacc[j][r] *= facr;
      }

      // pack P into PV A-fragments (natural k order by construction)
      union { i32x4 w; short8 h; } P0, P1;
      P0.w[0] = cvtpk(s[0][0], s[0][1]); P0.w[1] = cvtpk(s[0][2], s[0][3]);
      P0.w[2] = cvtpk(s[1][0], s[1][1]); P0.w[3] = cvtpk(s[1][2], s[1][3]);
      P1.w[0] = cvtpk(s[2][0], s[2][1]); P1.w[1] = cvtpk(s[2][2], s[2][3]);
      P1.w[2] = cvtpk(s[3][0], s[3][1]); P1.w[3] = cvtpk(s[3][2], s[3][3]);

      __builtin_amdgcn_s_setprio(1);
      #pragma unroll
      for (int j = 0; j < 4; j++){
        const int row = j * 16 + c15;
        const int sw = (row & 7) << 4;
        const short8 v0 = *(const short8*)(vbase + row * 128 + ((g * 16) ^ sw));
        const short8 v1 = *(const short8*)(vbase + row * 128 + ((g * 16 + 64) ^ sw));
        oacc[j] = __builtin_amdgcn_mfma_f32_16x16x32_bf16(P0.h, v0, oacc[j], 0, 0, 0);
        oacc[j] = __builtin_amdgcn_mfma_f32_16x16x32_bf16(P1.h, v1, oacc[j], 0, 0, 0);
      }
      __builtin_amdgcn_s_setprio(0);

      __syncthreads();   // drains prefetch vmcnt; next tile ready
      cur ^= 1;
    }

    const float invl = 1.f / lst;
    #pragma unroll
    for (int r = 0; r < 4; r++){
      const float invr = __shfl(invl, (lane & 48) | (g * 4 + r));
      #pragma unroll
      for (int j = 0; j < 4; j++){
        const int row = qt * 64 + w * 16 + g * 4 + r;
        const int col = h * 64 + j * 16 + c15;
        Y[((size_t)(b * T_SZ + row)) * C_SZ + col] = f2bf(oacc[j][r] * invr);
      }
    }
  }
}

extern "C" void kernel_launch(void* const* d_in, const int* in_sizes, int n_in,
                              void* d_out, int out_size, void* d_ws, size_t ws_size,
                              hipStream_t stream)
{
  const float* x      = (const float*)d_in[0];
  const float* w_qkv  = (const float*)d_in[1];
  const float* b_qkv  = (const float*)d_in[2];
  const float* w_proj = (const float*)d_in[3];
  const float* b_proj = (const float*)d_in[4];
  float* out = (float*)d_out;
  char* ws = (char*)d_ws;

  unsigned short* xb     = (unsigned short*)(ws);               // 16 MB
  unsigned short* wqkvT  = (unsigned short*)(ws + 16777216);    // 6 MB
  unsigned short* wprojT = (unsigned short*)(ws + 23068672);    // 2 MB
  unsigned short* Qw     = (unsigned short*)(ws + 25165824);    // 16 MB
  unsigned short* Kw     = (unsigned short*)(ws + 41943040);    // 16 MB
  unsigned short* Vw     = (unsigned short*)(ws + 58720256);    // 16 MB (transposed [bh,d,t])
  unsigned short* Yw     = (unsigned short*)(ws + 75497472);    // 16 MB

  cvt_bf16_kernel<<<8192, 256, 0, stream>>>(x, xb, 8388608 / 4);
  tconv_kernel<<<dim3(96, 32), dim3(32, 8), 0, stream>>>(w_qkv, wqkvT, 1024, 3072);
  tconv_kernel<<<dim3(32, 32), dim3(32, 8), 0, stream>>>(w_proj, wprojT, 1024, 1024);
  gemm_bt_kernel<0><<<dim3(64, 24), 256, 0, stream>>>(xb, wqkvT, b_qkv, Qw, Kw, Vw, nullptr, 8192, 3072, 1024);
  attn_kernel<<<dim3(16, 64), 256, 0, stream>>>(Qw, Kw, Vw, Yw);
  gemm_bt_kernel<1><<<dim3(64, 8), 256, 0, stream>>>(Yw, wprojT, b_proj, nullptr, nullptr, nullptr, out, 8192, 1024, 1024);
}